// Round 3
// baseline (4042.060 us; speedup 1.0000x reference)
//
#include <hip/hip_runtime.h>
#include <hip/hip_bf16.h>

#define Bsz 128
#define Tsz 1024
#define Dsz 128
#define Hsz 512
#define NBLK 256
#define NXC 4    // x K-chunks (128 / 32)
#define NHC 16   // h K-chunks (512 / 32)

typedef __attribute__((ext_vector_type(8))) short short8;
typedef __attribute__((ext_vector_type(4))) float f4;
typedef unsigned long long u64;

__device__ __forceinline__ unsigned short bf16_rne(float f) {
  unsigned u = __builtin_bit_cast(unsigned, f);
  u += 0x7fffu + ((u >> 16) & 1u);
  return (unsigned short)(u >> 16);
}
__device__ __forceinline__ float sigmoid_(float v) { return 1.f / (1.f + __expf(-v)); }
__device__ __forceinline__ float tanh_(float v) {
  v = fminf(fmaxf(v, -15.f), 15.f);           // avoid inf/inf
  float e = __expf(2.f * v);
  return (e - 1.f) / (e + 1.f);
}

// Persistent LSTM v3:
//  - wave computes ALL 4 gates for 4 cols (B-col map n = g*4 + c): gate combine
//    via 3 shfl_xor in-wave, no LDS round trip, no barrier. Lane (q,g,c) updates
//    exactly cell (row 4q+g, col 4w+c); 4x4 shuffle transpose -> one u64 store
//    per row (c==0 lanes).
//  - flags strided one per 128B line; ONLY wave 0 polls (32 lanes x 32 lines),
//    relays via LDS token -> kills the single-line LLC hammering of R2.
//  - x fragments double-buffered in LDS, staged for t+1 during step t's
//    store-drain window (bar3(t) < bar2(t+1) orders buffer reuse).
//  - 2 barriers/step: bar2 (h LDS ready), bar3 (vmcnt drain before flag).
__global__ __launch_bounds__(256, 1) void lstm_persist(
    const float* __restrict__ x, const float* __restrict__ W_ih,
    const float* __restrict__ W_hh, const float* __restrict__ b_ih,
    const float* __restrict__ b_hh, const float* __restrict__ W_fc,
    const float* __restrict__ b_fc, float* __restrict__ out,
    int* flags, unsigned short* hb0, unsigned short* hb1)
{
  const int bx = blockIdx.x;
  const int bt = bx & 7, ks = bx >> 3;     // 8 groups x 32 blocks
  const int b0 = bt << 4, k0 = ks << 4;
  const int tx = threadIdx.x;
  const int wave = tx >> 6, lane = tx & 63;
  const int m = lane & 15, quad = lane >> 4;
  const int g_own = (lane >> 2) & 3, c_own = lane & 3;
  const int mycol = k0 + wave * 4 + c_own;   // this lane's hidden column
  const int myrow = b0 + quad * 4 + g_own;   // this lane's batch row

  __shared__ short8 A_x[2][NXC][64];   // x fragments, double-buffered (8 KB)
  __shared__ short8 A_h[NHC][64];      // h fragments (16 KB)
  __shared__ float fc_red[16][16];
  __shared__ int token;

  int* gflags = flags + bt * 1024;     // 32 flags x 32-int (128 B) stride

  // ---- W fragments in registers: wave w, B-col n=(g,c) -> W row g*H + k0+4w+c
  short8 wfrag[NXC + NHC];
  {
    const int j = g_own * Hsz + k0 + wave * 4 + c_own;
    #pragma unroll
    for (int kc = 0; kc < NXC + NHC; ++kc) {
      const int kk = kc * 32 + quad * 8;
      const float* src = (kk < Dsz) ? (W_ih + (size_t)j * Dsz + kk)
                                    : (W_hh + (size_t)j * Hsz + (kk - Dsz));
      const f4* sv = (const f4*)src;
      f4 v0 = sv[0], v1 = sv[1];
      short8 w;
      w[0] = bf16_rne(v0[0]); w[1] = bf16_rne(v0[1]);
      w[2] = bf16_rne(v0[2]); w[3] = bf16_rne(v0[3]);
      w[4] = bf16_rne(v1[0]); w[5] = bf16_rne(v1[1]);
      w[6] = bf16_rne(v1[2]); w[7] = bf16_rne(v1[3]);
      wfrag[kc] = w;
    }
  }
  const float bias0 = b_ih[0 * Hsz + mycol] + b_hh[0 * Hsz + mycol];
  const float bias1 = b_ih[1 * Hsz + mycol] + b_hh[1 * Hsz + mycol];
  const float bias2 = b_ih[2 * Hsz + mycol] + b_hh[2 * Hsz + mycol];
  const float bias3 = b_ih[3 * Hsz + mycol] + b_hh[3 * Hsz + mycol];
  float c_reg = 0.f;                   // cell state for (myrow, mycol)

  // ---- pre-loop: stage x(0) into buf 0, zero A_h, init token
  {
    const f4* xv = (const f4*)(x + (size_t)(b0 + m) * (Tsz * Dsz) + wave * 32 + quad * 8);
    f4 v0 = xv[0], v1 = xv[1];
    short8 a;
    a[0] = bf16_rne(v0[0]); a[1] = bf16_rne(v0[1]);
    a[2] = bf16_rne(v0[2]); a[3] = bf16_rne(v0[3]);
    a[4] = bf16_rne(v1[0]); a[5] = bf16_rne(v1[1]);
    a[6] = bf16_rne(v1[2]); a[7] = bf16_rne(v1[3]);
    A_x[0][wave][lane] = a;
    short8 z = {0, 0, 0, 0, 0, 0, 0, 0};
    #pragma unroll
    for (int q = 0; q < 4; ++q) A_h[wave * 4 + q][lane] = z;
    if (tx == 0) token = 0;
  }

  for (int t = 0; t < Tsz; ++t) {
    unsigned short* hnext = (t & 1) ? hb1 : hb0;
    const unsigned short* hprev = (t & 1) ? hb0 : hb1;

    if (t > 0) {
      if (wave == 0) {  // only wave 0 polls LLC; 1 lane per 128B flag line
        const int fi = (lane & 31) * 32;
        for (;;) {
          int f = __hip_atomic_load(gflags + fi, __ATOMIC_RELAXED, __HIP_MEMORY_SCOPE_AGENT);
          if (__all(f >= t)) break;
          __builtin_amdgcn_s_sleep(1);
        }
        __hip_atomic_store(&token, t, __ATOMIC_RELAXED, __HIP_MEMORY_SCOPE_WORKGROUP);
      } else {          // cheap LDS spin
        while (__hip_atomic_load(&token, __ATOMIC_RELAXED, __HIP_MEMORY_SCOPE_WORKGROUP) < t) {}
      }
      // stage this wave's 4 h chunks from LLC
      #pragma unroll
      for (int q = 0; q < 4; ++q) {
        const int hc = wave * 4 + q;
        const u64* p = (const u64*)(hprev + (size_t)(b0 + m) * Hsz + hc * 32 + quad * 8);
        u64 lo = __hip_atomic_load(p,     __ATOMIC_RELAXED, __HIP_MEMORY_SCOPE_AGENT);
        u64 hi = __hip_atomic_load(p + 1, __ATOMIC_RELAXED, __HIP_MEMORY_SCOPE_AGENT);
        u64* dst = (u64*)&A_h[hc][lane];
        dst[0] = lo; dst[1] = hi;
      }
    }
    __syncthreads();   // bar2: A_h (and prev-staged A_x) ready

    // ---- 20 MFMA, W in regs, A from LDS
    const int xb = t & 1;
    f4 acc0 = {0.f, 0.f, 0.f, 0.f}, acc1 = {0.f, 0.f, 0.f, 0.f};
    acc0 = __builtin_amdgcn_mfma_f32_16x16x32_bf16(A_x[xb][0][lane], wfrag[0], acc0, 0, 0, 0);
    acc1 = __builtin_amdgcn_mfma_f32_16x16x32_bf16(A_x[xb][1][lane], wfrag[1], acc1, 0, 0, 0);
    acc0 = __builtin_amdgcn_mfma_f32_16x16x32_bf16(A_x[xb][2][lane], wfrag[2], acc0, 0, 0, 0);
    acc1 = __builtin_amdgcn_mfma_f32_16x16x32_bf16(A_x[xb][3][lane], wfrag[3], acc1, 0, 0, 0);
    #pragma unroll
    for (int hc = 0; hc < NHC; hc += 2) {
      acc0 = __builtin_amdgcn_mfma_f32_16x16x32_bf16(A_h[hc][lane],     wfrag[NXC + hc],     acc0, 0, 0, 0);
      acc1 = __builtin_amdgcn_mfma_f32_16x16x32_bf16(A_h[hc + 1][lane], wfrag[NXC + hc + 1], acc1, 0, 0, 0);
    }
    f4 acc = acc0 + acc1;   // reg r = preact(gate g s.t. ..., row 4q+r? no: row 4q+r, col n)

    // ---- in-wave gate gather: lane (q,g,c) wants preact[tg][row 4q+g][col 4w+c]
    // source for tg is lane^((g^tg)<<2), sending its acc[reg = its_g ^ mask_g].
    float a01 = (g_own & 1) ? acc[1] : acc[0];
    float a23 = (g_own & 1) ? acc[3] : acc[2];
    float own = (g_own & 2) ? a23 : a01;     // acc[g_own]
    float b01 = (g_own & 1) ? acc[0] : acc[1];
    float b23 = (g_own & 1) ? acc[2] : acc[3];
    float s1 = (g_own & 2) ? b23 : b01;      // acc[g_own^1]
    float s2 = (g_own & 2) ? a01 : a23;      // acc[g_own^2]
    float s3 = (g_own & 2) ? b01 : b23;      // acc[g_own^3]
    float x4  = __shfl_xor(s1, 4);           // p[g_own^1]
    float x8  = __shfl_xor(s2, 8);           // p[g_own^2]
    float x12 = __shfl_xor(s3, 12);          // p[g_own^3]
    // p[tg] = {own,x4,x8,x12}[g_own ^ tg]
    #define PICK(e) ({ int _e = (e); float _lo = (_e & 1) ? x4 : own; \
                       float _hi = (_e & 1) ? x12 : x8; (_e & 2) ? _hi : _lo; })
    float pi = PICK(g_own)     + bias0;
    float pf = PICK(g_own ^ 1) + bias1;
    float pg = PICK(g_own ^ 2) + bias2;
    float po = PICK(g_own ^ 3) + bias3;
    #undef PICK
    float iv = sigmoid_(pi), fv = sigmoid_(pf), ov = sigmoid_(po);
    float gv = tanh_(pg);
    c_reg = fv * c_reg + iv * gv;
    float hv = ov * tanh_(c_reg);

    // ---- pack row (4q+g) cols 4w..4w+4 via shfl transpose, u64 agent store
    float h1 = __shfl_xor(hv, 1);
    float h2 = __shfl_xor(hv, 2);
    float h3 = __shfl_xor(hv, 3);
    if (c_own == 0) {
      u64 packed = (u64)bf16_rne(hv) | ((u64)bf16_rne(h1) << 16)
                 | ((u64)bf16_rne(h2) << 32) | ((u64)bf16_rne(h3) << 48);
      u64* p = (u64*)(hnext + (size_t)myrow * Hsz + k0 + wave * 4);
      __hip_atomic_store(p, packed, __ATOMIC_RELAXED, __HIP_MEMORY_SCOPE_AGENT);
    }

    // ---- stage x(t+1) into other buffer (off critical path, fills drain window)
    if (t + 1 < Tsz) {
      const f4* xv = (const f4*)(x + (size_t)(b0 + m) * (Tsz * Dsz)
                                 + (size_t)(t + 1) * Dsz + wave * 32 + quad * 8);
      f4 v0 = xv[0], v1 = xv[1];
      short8 a;
      a[0] = bf16_rne(v0[0]); a[1] = bf16_rne(v0[1]);
      a[2] = bf16_rne(v0[2]); a[3] = bf16_rne(v0[3]);
      a[4] = bf16_rne(v1[0]); a[5] = bf16_rne(v1[1]);
      a[6] = bf16_rne(v1[2]); a[7] = bf16_rne(v1[3]);
      A_x[(t + 1) & 1][wave][lane] = a;
    }

    __syncthreads();   // bar3: drains all waves' h stores (vmcnt) before flag
    if (tx == 0)
      __hip_atomic_store(gflags + ks * 32, t + 1, __ATOMIC_RELAXED, __HIP_MEMORY_SCOPE_AGENT);
  }

  // ---- final FC: out[b] = sigmoid(h_last . W_fc + b_fc), ks==0 blocks
  if (ks == 0) {
    const int k_l = tx & 15, b_l = tx >> 4;
    const int fi = (lane & 31) * 32;
    for (;;) {
      int f = __hip_atomic_load(gflags + fi, __ATOMIC_RELAXED, __HIP_MEMORY_SCOPE_AGENT);
      if (__all(f >= Tsz)) break;
      __builtin_amdgcn_s_sleep(1);
    }
    const u64* p = (const u64*)(hb1 + (size_t)(b0 + b_l) * Hsz + k_l * 32);
    float partial = 0.f;
    #pragma unroll
    for (int q = 0; q < 8; ++q) {
      u64 v = __hip_atomic_load(p + q, __ATOMIC_RELAXED, __HIP_MEMORY_SCOPE_AGENT);
      #pragma unroll
      for (int e = 0; e < 4; ++e) {
        unsigned hv16 = (unsigned)((v >> (16 * e)) & 0xffffu);
        partial += __builtin_bit_cast(float, hv16 << 16) * W_fc[k_l * 32 + q * 4 + e];
      }
    }
    fc_red[b_l][k_l] = partial;
    __syncthreads();
    if (k_l == 0) {
      float s = b_fc[0];
      #pragma unroll
      for (int e = 0; e < 16; ++e) s += fc_red[b_l][e];
      out[b0 + b_l] = sigmoid_(s);
    }
  }
}

extern "C" void kernel_launch(void* const* d_in, const int* in_sizes, int n_in,
                              void* d_out, int out_size, void* d_ws, size_t ws_size,
                              hipStream_t stream) {
  const float* x    = (const float*)d_in[0];
  const float* W_ih = (const float*)d_in[1];
  const float* W_hh = (const float*)d_in[2];
  const float* b_ih = (const float*)d_in[3];
  const float* b_hh = (const float*)d_in[4];
  const float* W_fc = (const float*)d_in[5];
  const float* b_fc = (const float*)d_in[6];
  float* out = (float*)d_out;
  char* ws = (char*)d_ws;
  int* flags = (int*)ws;                                   // 8 groups x 32 flags x 128B
  unsigned short* hb0 = (unsigned short*)(ws + 65536);
  unsigned short* hb1 = (unsigned short*)(ws + 65536 + (size_t)Bsz * Hsz * 2);
  hipMemsetAsync(ws, 0, 32768, stream);                    // flags := 0
  lstm_persist<<<NBLK, 256, 0, stream>>>(x, W_ih, W_hh, b_ih, b_hh, W_fc, b_fc,
                                         out, flags, hb0, hb1);
}

// Round 4
// 3791.560 us; speedup vs baseline: 1.0661x; 1.0661x over previous
//
#include <hip/hip_runtime.h>
#include <hip/hip_bf16.h>

#define Bsz 128
#define Tsz 1024
#define Dsz 128
#define Hsz 512
#define NBLK 256
#define NXC 4    // x K-chunks (128/32)
#define NHC 16   // h K-chunks (512/32)

typedef __attribute__((ext_vector_type(8))) short short8;
typedef __attribute__((ext_vector_type(4))) float f4;
typedef unsigned long long u64;

__device__ __forceinline__ unsigned short bf16_rne(float f) {
  unsigned u = __builtin_bit_cast(unsigned, f);
  u += 0x7fffu + ((u >> 16) & 1u);
  return (unsigned short)(u >> 16);
}
__device__ __forceinline__ float sigmoid_(float v) { return 1.f / (1.f + __expf(-v)); }
__device__ __forceinline__ float tanh_(float v) {
  v = fminf(fmaxf(v, -15.f), 15.f);
  float e = __expf(2.f * v);
  return (e - 1.f) / (e + 1.f);
}
__device__ __forceinline__ short8 cvt8(f4 v0, f4 v1) {
  short8 a;
  a[0] = (short)bf16_rne(v0[0]); a[1] = (short)bf16_rne(v0[1]);
  a[2] = (short)bf16_rne(v0[2]); a[3] = (short)bf16_rne(v0[3]);
  a[4] = (short)bf16_rne(v1[0]); a[5] = (short)bf16_rne(v1[1]);
  a[6] = (short)bf16_rne(v1[2]); a[7] = (short)bf16_rne(v1[3]);
  return a;
}

// Persistent LSTM v4 = R2 skeleton + targeted fixes:
//  - wave = gate (R2 mapping): gate exchange via LDS, epilogue thread=(b_l,k_l),
//    per-row 32B h stores from ONE wave (coalesced; R3's per-wave 8B frag stores
//    caused 4x WRITE_SIZE).
//  - flags strided 128B/line (keeps R3 fix); all 4 waves poll directly.
//  - x ENTIRELY off critical path: each wave redundantly holds the full 16x128
//    x tile as 4 reg fragments (loaded+converted at prior step's tail, L2-hot);
//    the 4 x-MFMAs run BEFORE the poll. No A_x LDS, no extra barrier.
//  - h: agent-scope relaxed atomics to LLC (fence-free coherence, R2-proven).
__global__ __launch_bounds__(256, 1) void lstm_persist(
    const float* __restrict__ x, const float* __restrict__ W_ih,
    const float* __restrict__ W_hh, const float* __restrict__ b_ih,
    const float* __restrict__ b_hh, const float* __restrict__ W_fc,
    const float* __restrict__ b_fc, float* __restrict__ out,
    int* flags, unsigned short* hb0, unsigned short* hb1)
{
  const int bx = blockIdx.x;
  const int bt = bx & 7, ks = bx >> 3;     // 8 groups x 32 blocks (group ~ one XCD)
  const int b0 = bt << 4, k0 = ks << 4;
  const int tx = threadIdx.x;
  const int wave = tx >> 6, lane = tx & 63;
  const int m = lane & 15, quad = lane >> 4;
  const int k_l = tx & 15, b_l = tx >> 4;  // epilogue ownership: (b_l, k_l)

  __shared__ short8 A_h[NHC][64];      // 16 KB h fragments
  __shared__ f4 gates_lds[4][64];      // 4 KB per-gate D fragments
  __shared__ float fc_red[16][16];

  int* gflags = flags + bt * 1024;     // 32 flags x 128 B stride per group

  // ---- W fragments in registers (wave = gate) ----
  short8 wfrag[NXC + NHC];
  {
    const int j = wave * Hsz + k0 + m;   // W row = output column n
    #pragma unroll
    for (int kc = 0; kc < NXC + NHC; ++kc) {
      const int kk = kc * 32 + quad * 8;
      const float* src = (kk < Dsz) ? (W_ih + (size_t)j * Dsz + kk)
                                    : (W_hh + (size_t)j * Hsz + (kk - Dsz));
      const f4* sv = (const f4*)src;
      wfrag[kc] = cvt8(sv[0], sv[1]);
    }
  }
  float bias[4];
  #pragma unroll
  for (int g = 0; g < 4; ++g)
    bias[g] = b_ih[g * Hsz + k0 + k_l] + b_hh[g * Hsz + k0 + k_l];
  float c_reg = 0.f;

  // ---- pre-loop: x(0) into regs (full tile per wave), zero A_h ----
  const float* xbase = x + (size_t)(b0 + m) * (Tsz * Dsz);
  short8 xa[NXC];
  #pragma unroll
  for (int kc = 0; kc < NXC; ++kc) {
    const f4* xv = (const f4*)(xbase + kc * 32 + quad * 8);
    xa[kc] = cvt8(xv[0], xv[1]);
  }
  {
    short8 z = {0, 0, 0, 0, 0, 0, 0, 0};
    #pragma unroll
    for (int q = 0; q < 4; ++q) A_h[wave * 4 + q][lane] = z;
  }

  for (int t = 0; t < Tsz; ++t) {
    unsigned short* hnext = (t & 1) ? hb1 : hb0;
    const unsigned short* hprev = (t & 1) ? hb0 : hb1;

    // ---- x-part GEMM: no h dependence, runs before/during the wait ----
    f4 acc0 = {0.f, 0.f, 0.f, 0.f}, acc1 = {0.f, 0.f, 0.f, 0.f};
    acc0 = __builtin_amdgcn_mfma_f32_16x16x32_bf16(xa[0], wfrag[0], acc0, 0, 0, 0);
    acc1 = __builtin_amdgcn_mfma_f32_16x16x32_bf16(xa[1], wfrag[1], acc1, 0, 0, 0);
    acc0 = __builtin_amdgcn_mfma_f32_16x16x32_bf16(xa[2], wfrag[2], acc0, 0, 0, 0);
    acc1 = __builtin_amdgcn_mfma_f32_16x16x32_bf16(xa[3], wfrag[3], acc1, 0, 0, 0);

    // ---- prefetch x(t+1) (plain cached loads, in flight during poll) ----
    f4 q0, q1, q2, q3, q4, q5, q6, q7;
    if (t + 1 < Tsz) {
      const float* xp = xbase + (size_t)(t + 1) * Dsz + quad * 8;
      q0 = ((const f4*)(xp))[0];      q1 = ((const f4*)(xp))[1];
      q2 = ((const f4*)(xp + 32))[0]; q3 = ((const f4*)(xp + 32))[1];
      q4 = ((const f4*)(xp + 64))[0]; q5 = ((const f4*)(xp + 64))[1];
      q6 = ((const f4*)(xp + 96))[0]; q7 = ((const f4*)(xp + 96))[1];
    }

    if (t > 0) {
      // all 4 waves poll; one 128B line per flag
      const int fi = (lane & 31) * 32;
      for (;;) {
        int f = __hip_atomic_load(gflags + fi, __ATOMIC_RELAXED, __HIP_MEMORY_SCOPE_AGENT);
        if (__all(f >= t)) break;
        __builtin_amdgcn_s_sleep(1);
      }
      // h loads (LLC) -> regs -> LDS, this wave's 4 chunks
      u64 hv0[4], hv1[4];
      #pragma unroll
      for (int q = 0; q < 4; ++q) {
        const int hc = wave * 4 + q;
        const u64* p = (const u64*)(hprev + (size_t)(b0 + m) * Hsz + hc * 32 + quad * 8);
        hv0[q] = __hip_atomic_load(p,     __ATOMIC_RELAXED, __HIP_MEMORY_SCOPE_AGENT);
        hv1[q] = __hip_atomic_load(p + 1, __ATOMIC_RELAXED, __HIP_MEMORY_SCOPE_AGENT);
      }
      #pragma unroll
      for (int q = 0; q < 4; ++q) {
        u64* dst = (u64*)&A_h[wave * 4 + q][lane];
        dst[0] = hv0[q]; dst[1] = hv1[q];
      }
    }
    __syncthreads();   // bar_h: A_h ready

    // ---- h-part GEMM: 16 x (ds_read_b128 + mfma), 2 acc chains ----
    #pragma unroll
    for (int hc = 0; hc < NHC; hc += 2) {
      acc0 = __builtin_amdgcn_mfma_f32_16x16x32_bf16(A_h[hc][lane],     wfrag[NXC + hc],     acc0, 0, 0, 0);
      acc1 = __builtin_amdgcn_mfma_f32_16x16x32_bf16(A_h[hc + 1][lane], wfrag[NXC + hc + 1], acc1, 0, 0, 0);
    }
    gates_lds[wave][lane] = acc0 + acc1;   // D[b=quad*4+r][n=lane&15], gate=wave
    __syncthreads();   // bar_g

    { // ---- gate combine + state update: thread owns (b_l, k_l) ----
      const int lp = ((b_l >> 2) << 4) + k_l;
      const int r = b_l & 3;
      float pi = gates_lds[0][lp][r] + bias[0];
      float pf = gates_lds[1][lp][r] + bias[1];
      float pg = gates_lds[2][lp][r] + bias[2];
      float po = gates_lds[3][lp][r] + bias[3];
      float iv = sigmoid_(pi), fv = sigmoid_(pf), ov = sigmoid_(po);
      float gv = tanh_(pg);
      c_reg = fv * c_reg + iv * gv;
      float hv = ov * tanh_(c_reg);
      // pack 4 cols -> one u64 store per k_l%4==0 lane (per-row 32B coalesced)
      float h1 = __shfl_xor(hv, 1);
      float h2 = __shfl_xor(hv, 2);
      float h3 = __shfl_xor(hv, 3);
      if ((k_l & 3) == 0) {
        u64 packed = (u64)bf16_rne(hv) | ((u64)bf16_rne(h1) << 16)
                   | ((u64)bf16_rne(h2) << 32) | ((u64)bf16_rne(h3) << 48);
        u64* p = (u64*)(hnext + (size_t)(b0 + b_l) * Hsz + k0 + k_l);
        __hip_atomic_store(p, packed, __ATOMIC_RELAXED, __HIP_MEMORY_SCOPE_AGENT);
      }
    }

    // ---- convert x(t+1) regs (fills the store-drain window) ----
    if (t + 1 < Tsz) {
      xa[0] = cvt8(q0, q1); xa[1] = cvt8(q2, q3);
      xa[2] = cvt8(q4, q5); xa[3] = cvt8(q6, q7);
    }

    __syncthreads();   // bar3: all waves' h stores drained (vmcnt) before flag
    if (tx == 0)
      __hip_atomic_store(gflags + ks * 32, t + 1, __ATOMIC_RELAXED, __HIP_MEMORY_SCOPE_AGENT);
  }

  // ---- final FC: out[b] = sigmoid(h_last . W_fc + b_fc), ks==0 blocks ----
  if (ks == 0) {
    const int fi = (lane & 31) * 32;
    for (;;) {
      int f = __hip_atomic_load(gflags + fi, __ATOMIC_RELAXED, __HIP_MEMORY_SCOPE_AGENT);
      if (__all(f >= Tsz)) break;
      __builtin_amdgcn_s_sleep(1);
    }
    const u64* p = (const u64*)(hb1 + (size_t)(b0 + b_l) * Hsz + k_l * 32);
    float partial = 0.f;
    #pragma unroll
    for (int q = 0; q < 8; ++q) {
      u64 v = __hip_atomic_load(p + q, __ATOMIC_RELAXED, __HIP_MEMORY_SCOPE_AGENT);
      #pragma unroll
      for (int e = 0; e < 4; ++e) {
        unsigned hv16 = (unsigned)((v >> (16 * e)) & 0xffffu);
        partial += __builtin_bit_cast(float, hv16 << 16) * W_fc[k_l * 32 + q * 4 + e];
      }
    }
    fc_red[b_l][k_l] = partial;
    __syncthreads();
    if (k_l == 0) {
      float s = b_fc[0];
      #pragma unroll
      for (int e = 0; e < 16; ++e) s += fc_red[b_l][e];
      out[b0 + b_l] = sigmoid_(s);
    }
  }
}

extern "C" void kernel_launch(void* const* d_in, const int* in_sizes, int n_in,
                              void* d_out, int out_size, void* d_ws, size_t ws_size,
                              hipStream_t stream) {
  const float* x    = (const float*)d_in[0];
  const float* W_ih = (const float*)d_in[1];
  const float* W_hh = (const float*)d_in[2];
  const float* b_ih = (const float*)d_in[3];
  const float* b_hh = (const float*)d_in[4];
  const float* W_fc = (const float*)d_in[5];
  const float* b_fc = (const float*)d_in[6];
  float* out = (float*)d_out;
  char* ws = (char*)d_ws;
  int* flags = (int*)ws;                                   // 8 groups x 32 flags x 128B
  unsigned short* hb0 = (unsigned short*)(ws + 65536);
  unsigned short* hb1 = (unsigned short*)(ws + 65536 + (size_t)Bsz * Hsz * 2);
  hipMemsetAsync(ws, 0, 32768, stream);                    // flags := 0
  lstm_persist<<<NBLK, 256, 0, stream>>>(x, W_ih, W_hh, b_ih, b_hh, W_fc, b_fc,
                                         out, flags, hb0, hb1);
}